// Round 12
// baseline (306.199 us; speedup 1.0000x reference)
//
#include <hip/hip_runtime.h>
#include <math.h>

#define NB 4
#define GH 64
#define GW 64
#define DM 128
#define MW 256
#define NF 10
#define NPTS 65536
#define ENCD 42
#define MT 128         // points per block: two 64-pt half-tiles A (rows 0-63) and B (64-127)
#define TPB 512
#define LDK 264        // act row stride in f16

typedef _Float16 f16x8 __attribute__((ext_vector_type(8)));
typedef __fp16 h16x2 __attribute__((ext_vector_type(2)));
typedef float f32x4 __attribute__((ext_vector_type(4)));

// d_ws: [0,8192) film fp32 (4x512); [8192,...) packed f16 weights.
// 16x16x32 B-frags: unit = (ktg*16 + nt)*64 + lane, 8 halves each.
#define KTU 8192
#define KT0 0
#define KT1 6
#define KT2 14
#define KT3 22
#define KT_TOTAL 30
#define NUNIT_MAIN (KT_TOTAL * 16 * 64)
#define NUNIT_OUT (8 * 64)
#define OUT_OFF ((size_t)NUNIT_MAIN * 8)

__device__ __forceinline__ float gelu_fast(float v) {
  const float t = v * v;
  const float w = fmaf(-0.10294324f, t, -2.3022082f);
  const float e = __builtin_amdgcn_exp2f(v * w);
  return v * __builtin_amdgcn_rcpf(1.0f + e);
}

__device__ __forceinline__ float tanh_fast(float v) {
  const float e = __builtin_amdgcn_exp2f(2.8853900818f * v);
  return 1.0f - 2.0f * __builtin_amdgcn_rcpf(1.0f + e);
}

// Fused prep: blocks [0,122) pack weights; blocks [122,126) compute film.
__global__ void prep_kernel(const float* __restrict__ w0, const float* __restrict__ w1,
                            const float* __restrict__ w2, const float* __restrict__ w3,
                            const float* __restrict__ wo,
                            const float* __restrict__ ctx, const float* __restrict__ wf,
                            const float* __restrict__ bf,
                            _Float16* __restrict__ wp, float* __restrict__ filmout) {
  if (blockIdx.x >= 122) {
    const int b = blockIdx.x - 122;
#pragma unroll
    for (int h = 0; h < 2; ++h) {
      const int j = threadIdx.x + h * 256;
      float acc = bf[j];
      for (int k = 0; k < DM; ++k)
        acc = fmaf(ctx[b * DM + k], wf[k * 512 + j], acc);
      filmout[b * 512 + j] = acc;
    }
    return;
  }
  const int u = blockIdx.x * 256 + threadIdx.x;
  const int lane = u & 63;
  if (u < NUNIT_MAIN) {
    const int v = u >> 6;
    const int nt = v & 15;
    const int ktg = v >> 4;
    const float* w; int ktl, K;
    if (ktg < KT1)      { w = w0; ktl = ktg - KT0; K = 170; }
    else if (ktg < KT2) { w = w1; ktl = ktg - KT1; K = 256; }
    else if (ktg < KT3) { w = w2; ktl = ktg - KT2; K = 256; }
    else                { w = w3; ktl = ktg - KT3; K = 256; }
    const int n = nt * 16 + (lane & 15);
    const int kbase = ktl * 32 + (lane >> 4) * 8;
    _Float16* dst = wp + (size_t)u * 8;
#pragma unroll
    for (int j = 0; j < 8; ++j) {
      const int k = kbase + j;
      dst[j] = (_Float16)((k < K) ? w[k * MW + n] : 0.0f);
    }
  } else {
    const int kt = (u - NUNIT_MAIN) >> 6;
    const int col = lane & 15;
    const int kbase = kt * 32 + (lane >> 4) * 8;
    _Float16* dst = wp + (size_t)u * 8;
#pragma unroll
    for (int j = 0; j < 8; ++j)
      dst[j] = (_Float16)((col < 3) ? wo[(kbase + j) * 3 + col] : 0.0f);
  }
}

__global__ __launch_bounds__(TPB, 4) void decoder_kernel(
    const float* __restrict__ grid, const float* __restrict__ coords,
    const float* __restrict__ b0, const float* __restrict__ b1,
    const float* __restrict__ b2, const float* __restrict__ b3,
    const float* __restrict__ bo,
    const float* __restrict__ film, const _Float16* __restrict__ wpack,
    float* __restrict__ out) {
  __shared__ _Float16 act[MT * LDK];   // 67584 B; rows 0-63 = tile A, 64-127 = tile B
  __shared__ float4 cco4[MT];          // 2048 B

  const int tid = threadIdx.x;
  const int lane = tid & 63;
  const int wc = tid >> 6;             // wave 0..7
  const int cq = wc & 3;               // column quarter: cols cq*64..cq*64+63
  const int rh32 = (wc >> 2) * 32;     // row half within the active 64-row tile
  const int b = blockIdx.x >> 9;
  const int n0 = (blockIdx.x & 511) * MT;

  // ---- per-point bilinear setup ----
  if (tid < MT) {
    const float x = coords[(size_t)(n0 + tid) * 2 + 0];
    const float y = coords[(size_t)(n0 + tid) * 2 + 1];
    const float cr = (x + 1.0f) * 0.5f * 63.0f;
    const float cc = (y + 1.0f) * 0.5f * 63.0f;
    const float r0f = floorf(cr), q0f = floorf(cc);
    const int r0 = min(max((int)r0f, 0), GH - 1);
    const int q0 = min(max((int)q0f, 0), GW - 1);
    float4 v;
    v.x = __int_as_float(r0);
    v.y = __int_as_float(q0);
    v.z = cr - r0f;
    v.w = cc - q0f;
    cco4[tid] = v;
  }

  // ---- positional encoding (hw sin/cos, revolutions) + zero-pad 170..191 ----
  {
    const int p = tid & (MT - 1);
    const int j = tid >> 7;
    const float x = coords[(size_t)(n0 + p) * 2 + 0];
    const float y = coords[(size_t)(n0 + p) * 2 + 1];
    _Float16* row = act + p * LDK;
    if (j == 0) { row[0] = (_Float16)x; row[1] = (_Float16)y; }
    if (j == 1) {
      for (int c = ENCD + DM; c < ENCD + DM + 22; ++c) row[c] = (_Float16)0.0f;
    }
    for (int i = j; i < NF; i += 4) {
      const float sc = 0.5f * (float)(1 << i);
      const float rx = x * sc, ry = y * sc;
      const float fx = rx - floorf(rx);
      const float fy = ry - floorf(ry);
      row[2 + 4 * i + 0] = (_Float16)__builtin_amdgcn_sinf(fx);
      row[2 + 4 * i + 1] = (_Float16)__builtin_amdgcn_sinf(fy);
      row[2 + 4 * i + 2] = (_Float16)__builtin_amdgcn_cosf(fx);
      row[2 + 4 * i + 3] = (_Float16)__builtin_amdgcn_cosf(fy);
    }
  }
  __syncthreads();

  // ---- bilinear sampling, 4 channels/iter ----
  {
    const float* gb = grid + (size_t)b * (GH * GW * DM);
#pragma unroll
    for (int it = 0; it < (MT * DM / 4) / TPB; ++it) {
      const int idx = it * TPB + tid;
      const int p = idx >> 5;
      const int c = (idx & 31) * 4;
      const float4 cc4 = cco4[p];
      const int r0 = __float_as_int(cc4.x);
      const int q0 = __float_as_int(cc4.y);
      const float frr = cc4.z, frc = cc4.w;
      const int r1 = min(r0 + 1, GH - 1), q1 = min(q0 + 1, GW - 1);
      const float4 v00 = *(const float4*)(gb + (size_t)(r0 * GW + q0) * DM + c);
      const float4 v01 = *(const float4*)(gb + (size_t)(r0 * GW + q1) * DM + c);
      const float4 v10 = *(const float4*)(gb + (size_t)(r1 * GW + q0) * DM + c);
      const float4 v11 = *(const float4*)(gb + (size_t)(r1 * GW + q1) * DM + c);
      float4 vt, vb, vv;
      vt.x = fmaf(v01.x - v00.x, frc, v00.x);
      vt.y = fmaf(v01.y - v00.y, frc, v00.y);
      vt.z = fmaf(v01.z - v00.z, frc, v00.z);
      vt.w = fmaf(v01.w - v00.w, frc, v00.w);
      vb.x = fmaf(v11.x - v10.x, frc, v10.x);
      vb.y = fmaf(v11.y - v10.y, frc, v10.y);
      vb.z = fmaf(v11.z - v10.z, frc, v10.z);
      vb.w = fmaf(v11.w - v10.w, frc, v10.w);
      vv.x = fmaf(vb.x - vt.x, frr, vt.x);
      vv.y = fmaf(vb.y - vt.y, frr, vt.y);
      vv.z = fmaf(vb.z - vt.z, frr, vt.z);
      vv.w = fmaf(vb.w - vt.w, frr, vt.w);
      const h16x2 lo = __builtin_amdgcn_cvt_pkrtz(vv.x, vv.y);
      const h16x2 hi = __builtin_amdgcn_cvt_pkrtz(vv.z, vv.w);
      *(h16x2*)(act + p * LDK + ENCD + c) = lo;
      *(h16x2*)(act + p * LDK + ENCD + c + 2) = hi;
    }
  }

  // ---- FiLM params: this wave owns 4 n-tiles (cols cq*64 + nt*16 + 0..15) ----
  const int colbase = cq * 64 + (lane & 15);
  float g1[4], btv[4];
#pragma unroll
  for (int nt = 0; nt < 4; ++nt) {
    g1[nt] = film[b * 512 + colbase + nt * 16] + 1.0f;
    btv[nt] = film[b * 512 + MW + colbase + nt * 16];
  }
  __syncthreads();

  const int arow = lane & 15;
  const int kq = (lane >> 4) * 8;

  f32x4 accA[2][4], accB[2][4];

  // fragment loaders (wave tile = 2 m-tiles x 4 n-tiles = 32 rows x 64 cols)
  auto loadB = [&](const _Float16* __restrict__ wl, int kt, f16x8 (&bfr)[4]) {
#pragma unroll
    for (int nt = 0; nt < 4; ++nt)
      bfr[nt] = *(const f16x8*)(wl + ((size_t)((kt * 16 + cq * 4 + nt) * 64 + lane)) * 8);
  };
  auto loadA = [&](int T, int kt, f16x8 (&afr)[2]) {
    const int kof = kt * 32 + kq;
#pragma unroll
    for (int mt = 0; mt < 2; ++mt)
      afr[mt] = *(const f16x8*)(act + (T * 64 + rh32 + mt * 16 + arow) * LDK + kof);
  };
  auto domfma = [&](f16x8 (&afr)[2], f16x8 (&bfr)[4], f32x4 (&acc)[2][4]) {
#pragma unroll
    for (int mt = 0; mt < 2; ++mt)
#pragma unroll
      for (int nt = 0; nt < 4; ++nt)
        acc[mt][nt] = __builtin_amdgcn_mfma_f32_16x16x32_f16(afr[mt], bfr[nt], acc[mt][nt], 0, 0, 0);
  };

  // one epilogue group (of 8) for tile T: g -> (mt = g>>2, nt = g&3)
  auto epi_group = [&](int g, int T, f32x4 (&acc)[2][4], const float* cbv) {
    const int mt = g >> 2, nt = g & 3;
    const int col = cq * 64 + nt * 16 + (lane & 15);
    const int rowb = T * 64 + rh32 + mt * 16 + (lane >> 4) * 4;
#pragma unroll
    for (int r = 0; r < 4; ++r) {
      const float v = fmaf(acc[mt][nt][r], g1[nt], cbv[nt]);
      act[(rowb + r) * LDK + col] = (_Float16)gelu_fast(v);
    }
  };

  auto zero = [&](f32x4 (&acc)[2][4]) {
#pragma unroll
    for (int mt = 0; mt < 2; ++mt)
#pragma unroll
      for (int nt = 0; nt < 4; ++nt)
        acc[mt][nt] = (f32x4){0.f, 0.f, 0.f, 0.f};
  };

  float cbv[4];
  auto set_cb = [&](const float* __restrict__ bl) {
#pragma unroll
    for (int nt = 0; nt < 4; ++nt)
      cbv[nt] = fmaf(bl[colbase + nt * 16], g1[nt], btv[nt]);
  };

  // Pipelined segment: Kt ksteps for tile Tk into accK (B-frags 2 ahead in a
  // rolling 2-buffer), plus optionally the 8 epilogue groups of tile Te.
  auto run_seg = [&](const _Float16* __restrict__ wl, int Kt, int Tk,
                     f32x4 (&accK)[2][4], bool do_epi, int Te,
                     f32x4 (&accE)[2][4]) {
    f16x8 bb[2][4];
    loadB(wl, 0, bb[0]);
    if (Kt > 1) loadB(wl, 1, bb[1]);
#pragma unroll
    for (int s = 0; s < 8; ++s) {
      if (s < Kt) {
        f16x8 afr[2];
        loadA(Tk, s, afr);
        domfma(afr, bb[s & 1], accK);
        if (s + 2 < Kt) loadB(wl, s + 2, bb[s & 1]);
      }
      if (do_epi) epi_group(s, Te, accE, cbv);
    }
  };

  const _Float16* wp0 = wpack + (size_t)KT0 * KTU;
  const _Float16* wp1 = wpack + (size_t)KT1 * KTU;
  const _Float16* wp2 = wpack + (size_t)KT2 * KTU;
  const _Float16* wp3 = wpack + (size_t)KT3 * KTU;

  // seg0: K(A,0)
  zero(accA);
  run_seg(wp0, 6, 0, accA, false, 0, accB);
  __syncthreads();

  // seg1: E(A,0) + K(B,0)
  zero(accB); set_cb(b0);
  run_seg(wp0, 6, 1, accB, true, 0, accA);
  __syncthreads();

  // seg2: E(B,0) + K(A,1)
  zero(accA); set_cb(b0);
  run_seg(wp1, 8, 0, accA, true, 1, accB);
  __syncthreads();

  // seg3: E(A,1) + K(B,1)
  zero(accB); set_cb(b1);
  run_seg(wp1, 8, 1, accB, true, 0, accA);
  __syncthreads();

  // seg4: E(B,1) + K(A,2)
  zero(accA); set_cb(b1);
  run_seg(wp2, 8, 0, accA, true, 1, accB);
  __syncthreads();

  // seg5: E(A,2) + K(B,2)
  zero(accB); set_cb(b2);
  run_seg(wp2, 8, 1, accB, true, 0, accA);
  __syncthreads();

  // seg6: E(B,2) + K(A,3)
  zero(accA); set_cb(b2);
  run_seg(wp3, 8, 0, accA, true, 1, accB);
  __syncthreads();

  // seg7: E(A,3) + K(B,3)
  zero(accB); set_cb(b3);
  run_seg(wp3, 8, 1, accB, true, 0, accA);
  __syncthreads();

  // seg8: E(B,3) [all waves] + Kout(tile A) [waves 0..3] + store A
  {
    set_cb(b3);
    const _Float16* wob = wpack + OUT_OFF;
    f32x4 oacc = (f32x4){0.f, 0.f, 0.f, 0.f};
    const int rb = (wc & 3) * 16 + ((wc < 4) ? 0 : 64);  // wave's 16-row slice
#pragma unroll
    for (int s = 0; s < 8; ++s) {
      if (wc < 4) {
        const f16x8 bfr = *(const f16x8*)(wob + (size_t)(s * 64 + lane) * 8);
        const f16x8 afr = *(const f16x8*)(act + (rb + arow) * LDK + s * 32 + kq);
        oacc = __builtin_amdgcn_mfma_f32_16x16x32_f16(afr, bfr, oacc, 0, 0, 0);
      }
      epi_group(s, 1, accB, cbv);
    }
    if (wc < 4) {
      const int col = lane & 15;
      if (col < 3) {
        const float bv = bo[col];
        const int rowb = rb + (lane >> 4) * 4;
#pragma unroll
        for (int r = 0; r < 4; ++r)
          out[((size_t)b * NPTS + n0 + rowb + r) * 3 + col] = tanh_fast(oacc[r] + bv);
      }
    }
    __syncthreads();

    // seg9: Kout(tile B) [waves 4..7] + store B
    if (wc >= 4) {
      f32x4 oacc2 = (f32x4){0.f, 0.f, 0.f, 0.f};
#pragma unroll
      for (int kt = 0; kt < 8; ++kt) {
        const f16x8 bfr = *(const f16x8*)(wob + (size_t)(kt * 64 + lane) * 8);
        const f16x8 afr = *(const f16x8*)(act + (rb + arow) * LDK + kt * 32 + kq);
        oacc2 = __builtin_amdgcn_mfma_f32_16x16x32_f16(afr, bfr, oacc2, 0, 0, 0);
      }
      const int col = lane & 15;
      if (col < 3) {
        const float bv = bo[col];
        const int rowb = rb + (lane >> 4) * 4;
#pragma unroll
        for (int r = 0; r < 4; ++r)
          out[((size_t)b * NPTS + n0 + rowb + r) * 3 + col] = tanh_fast(oacc2[r] + bv);
      }
    }
  }
}

extern "C" void kernel_launch(void* const* d_in, const int* in_sizes, int n_in,
                              void* d_out, int out_size, void* d_ws, size_t ws_size,
                              hipStream_t stream) {
  const float* grid   = (const float*)d_in[0];
  const float* ctx    = (const float*)d_in[1];
  const float* coords = (const float*)d_in[2];
  const float* w0 = (const float*)d_in[3];
  const float* b0 = (const float*)d_in[4];
  const float* w1 = (const float*)d_in[5];
  const float* b1 = (const float*)d_in[6];
  const float* w2 = (const float*)d_in[7];
  const float* b2 = (const float*)d_in[8];
  const float* w3 = (const float*)d_in[9];
  const float* b3 = (const float*)d_in[10];
  const float* wf = (const float*)d_in[11];
  const float* bf = (const float*)d_in[12];
  const float* wo = (const float*)d_in[13];
  const float* bo = (const float*)d_in[14];
  float* out = (float*)d_out;

  float* filmbuf = (float*)d_ws;
  _Float16* wpack = (_Float16*)((char*)d_ws + 8192);

  hipLaunchKernelGGL(prep_kernel, dim3(126), dim3(256), 0, stream,
                     w0, w1, w2, w3, wo, ctx, wf, bf, wpack, filmbuf);
  hipLaunchKernelGGL(decoder_kernel, dim3(NB * (NPTS / MT)), dim3(TPB), 0, stream,
                     grid, coords, b0, b1, b2, b3, bo, filmbuf, wpack, out);
}

// Round 13
// 279.505 us; speedup vs baseline: 1.0955x; 1.0955x over previous
//
#include <hip/hip_runtime.h>
#include <math.h>

#define NB 4
#define GH 64
#define GW 64
#define DM 128
#define MW 256
#define NF 10
#define NPTS 65536
#define ENCD 42
#define MT 128         // points per block: two 64-pt half-tiles A (rows 0-63) and B (64-127)
#define TPB 512
#define LDK 264        // act row stride in f16 (row base 528 B, 16B-aligned)

typedef _Float16 f16x8 __attribute__((ext_vector_type(8)));
typedef __fp16 h16x2 __attribute__((ext_vector_type(2)));
typedef __fp16 h16x4 __attribute__((ext_vector_type(4)));
typedef float f32x4 __attribute__((ext_vector_type(4)));

// d_ws: [0,8192) film fp32 (4x512); [8192,...) packed f16 weights.
// Fragment bytes unchanged from R8: unit = (ktg*16 + nt)*64 + lane, 8 halves.
// (B-frag of h·W == A-frag of Wt·ht — identical lane->(idx,k) map.)
#define KTU 8192
#define KT0 0
#define KT1 6
#define KT2 14
#define KT3 22
#define KT_TOTAL 30
#define NUNIT_MAIN (KT_TOTAL * 16 * 64)
#define NUNIT_OUT (8 * 64)
#define OUT_OFF ((size_t)NUNIT_MAIN * 8)

__device__ __forceinline__ float gelu_fast(float v) {
  const float t = v * v;
  const float w = fmaf(-0.10294324f, t, -2.3022082f);
  const float e = __builtin_amdgcn_exp2f(v * w);
  return v * __builtin_amdgcn_rcpf(1.0f + e);
}

__device__ __forceinline__ float tanh_fast(float v) {
  const float e = __builtin_amdgcn_exp2f(2.8853900818f * v);
  return 1.0f - 2.0f * __builtin_amdgcn_rcpf(1.0f + e);
}

// Fused prep: blocks [0,122) pack weights; blocks [122,126) compute film.
__global__ void prep_kernel(const float* __restrict__ w0, const float* __restrict__ w1,
                            const float* __restrict__ w2, const float* __restrict__ w3,
                            const float* __restrict__ wo,
                            const float* __restrict__ ctx, const float* __restrict__ wf,
                            const float* __restrict__ bf,
                            _Float16* __restrict__ wp, float* __restrict__ filmout) {
  if (blockIdx.x >= 122) {
    const int b = blockIdx.x - 122;
#pragma unroll
    for (int h = 0; h < 2; ++h) {
      const int j = threadIdx.x + h * 256;
      float acc = bf[j];
      for (int k = 0; k < DM; ++k)
        acc = fmaf(ctx[b * DM + k], wf[k * 512 + j], acc);
      filmout[b * 512 + j] = acc;
    }
    return;
  }
  const int u = blockIdx.x * 256 + threadIdx.x;
  const int lane = u & 63;
  if (u < NUNIT_MAIN) {
    const int v = u >> 6;
    const int nt = v & 15;
    const int ktg = v >> 4;
    const float* w; int ktl, K;
    if (ktg < KT1)      { w = w0; ktl = ktg - KT0; K = 170; }
    else if (ktg < KT2) { w = w1; ktl = ktg - KT1; K = 256; }
    else if (ktg < KT3) { w = w2; ktl = ktg - KT2; K = 256; }
    else                { w = w3; ktl = ktg - KT3; K = 256; }
    const int n = nt * 16 + (lane & 15);
    const int kbase = ktl * 32 + (lane >> 4) * 8;
    _Float16* dst = wp + (size_t)u * 8;
#pragma unroll
    for (int j = 0; j < 8; ++j) {
      const int k = kbase + j;
      dst[j] = (_Float16)((k < K) ? w[k * MW + n] : 0.0f);
    }
  } else {
    const int kt = (u - NUNIT_MAIN) >> 6;
    const int col = lane & 15;
    const int kbase = kt * 32 + (lane >> 4) * 8;
    _Float16* dst = wp + (size_t)u * 8;
#pragma unroll
    for (int j = 0; j < 8; ++j)
      dst[j] = (_Float16)((col < 3) ? wo[(kbase + j) * 3 + col] : 0.0f);
  }
}

__global__ __launch_bounds__(TPB, 4) void decoder_kernel(
    const float* __restrict__ grid, const float* __restrict__ coords,
    const float* __restrict__ b0, const float* __restrict__ b1,
    const float* __restrict__ b2, const float* __restrict__ b3,
    const float* __restrict__ bo,
    const float* __restrict__ film, const _Float16* __restrict__ wpack,
    float* __restrict__ out) {
  __shared__ _Float16 act[MT * LDK];   // 67584 B; rows 0-63 = tile A, 64-127 = tile B
  __shared__ float4 cco4[MT];          // 2048 B

  const int tid = threadIdx.x;
  const int lane = tid & 63;
  const int wc = tid >> 6;             // wave 0..7: owns CHANNELS wc*32..wc*32+31 (disjoint)
  const int b = blockIdx.x >> 9;
  const int n0 = (blockIdx.x & 511) * MT;

  // ---- per-point bilinear setup ----
  if (tid < MT) {
    const float x = coords[(size_t)(n0 + tid) * 2 + 0];
    const float y = coords[(size_t)(n0 + tid) * 2 + 1];
    const float cr = (x + 1.0f) * 0.5f * 63.0f;
    const float cc = (y + 1.0f) * 0.5f * 63.0f;
    const float r0f = floorf(cr), q0f = floorf(cc);
    const int r0 = min(max((int)r0f, 0), GH - 1);
    const int q0 = min(max((int)q0f, 0), GW - 1);
    float4 v;
    v.x = __int_as_float(r0);
    v.y = __int_as_float(q0);
    v.z = cr - r0f;
    v.w = cc - q0f;
    cco4[tid] = v;
  }

  // ---- positional encoding (hw sin/cos, revolutions) + zero-pad 170..191 ----
  {
    const int p = tid & (MT - 1);
    const int j = tid >> 7;
    const float x = coords[(size_t)(n0 + p) * 2 + 0];
    const float y = coords[(size_t)(n0 + p) * 2 + 1];
    _Float16* row = act + p * LDK;
    if (j == 0) { row[0] = (_Float16)x; row[1] = (_Float16)y; }
    if (j == 1) {
      for (int c = ENCD + DM; c < ENCD + DM + 22; ++c) row[c] = (_Float16)0.0f;
    }
    for (int i = j; i < NF; i += 4) {
      const float sc = 0.5f * (float)(1 << i);
      const float rx = x * sc, ry = y * sc;
      const float fx = rx - floorf(rx);
      const float fy = ry - floorf(ry);
      row[2 + 4 * i + 0] = (_Float16)__builtin_amdgcn_sinf(fx);
      row[2 + 4 * i + 1] = (_Float16)__builtin_amdgcn_sinf(fy);
      row[2 + 4 * i + 2] = (_Float16)__builtin_amdgcn_cosf(fx);
      row[2 + 4 * i + 3] = (_Float16)__builtin_amdgcn_cosf(fy);
    }
  }
  __syncthreads();

  // ---- bilinear sampling, 4 channels/iter ----
  {
    const float* gb = grid + (size_t)b * (GH * GW * DM);
#pragma unroll
    for (int it = 0; it < (MT * DM / 4) / TPB; ++it) {
      const int idx = it * TPB + tid;
      const int p = idx >> 5;
      const int c = (idx & 31) * 4;
      const float4 cc4 = cco4[p];
      const int r0 = __float_as_int(cc4.x);
      const int q0 = __float_as_int(cc4.y);
      const float frr = cc4.z, frc = cc4.w;
      const int r1 = min(r0 + 1, GH - 1), q1 = min(q0 + 1, GW - 1);
      const float4 v00 = *(const float4*)(gb + (size_t)(r0 * GW + q0) * DM + c);
      const float4 v01 = *(const float4*)(gb + (size_t)(r0 * GW + q1) * DM + c);
      const float4 v10 = *(const float4*)(gb + (size_t)(r1 * GW + q0) * DM + c);
      const float4 v11 = *(const float4*)(gb + (size_t)(r1 * GW + q1) * DM + c);
      float4 vt, vb, vv;
      vt.x = fmaf(v01.x - v00.x, frc, v00.x);
      vt.y = fmaf(v01.y - v00.y, frc, v00.y);
      vt.z = fmaf(v01.z - v00.z, frc, v00.z);
      vt.w = fmaf(v01.w - v00.w, frc, v00.w);
      vb.x = fmaf(v11.x - v10.x, frc, v10.x);
      vb.y = fmaf(v11.y - v10.y, frc, v10.y);
      vb.z = fmaf(v11.z - v10.z, frc, v10.z);
      vb.w = fmaf(v11.w - v10.w, frc, v10.w);
      vv.x = fmaf(vb.x - vt.x, frr, vt.x);
      vv.y = fmaf(vb.y - vt.y, frr, vt.y);
      vv.z = fmaf(vb.z - vt.z, frr, vt.z);
      vv.w = fmaf(vb.w - vt.w, frr, vt.w);
      const h16x2 lo = __builtin_amdgcn_cvt_pkrtz(vv.x, vv.y);
      const h16x2 hi = __builtin_amdgcn_cvt_pkrtz(vv.z, vv.w);
      *(h16x2*)(act + p * LDK + ENCD + c) = lo;
      *(h16x2*)(act + p * LDK + ENCD + c + 2) = hi;
    }
  }

  // ---- FiLM params: wave owns 2 channel-16-tiles; lane holds 4 consecutive
  //      channels (quad*4 + r) of each -> float4 loads ----
  const int chq0 = wc * 32 + (lane >> 4) * 4;   // + ntc*16
  f32x4 g1q[2], btq[2];
#pragma unroll
  for (int ntc = 0; ntc < 2; ++ntc) {
    f32x4 gm = *(const f32x4*)&film[b * 512 + chq0 + ntc * 16];
#pragma unroll
    for (int r = 0; r < 4; ++r) g1q[ntc][r] = gm[r] + 1.0f;
    btq[ntc] = *(const f32x4*)&film[b * 512 + MW + chq0 + ntc * 16];
  }
  __syncthreads();

  const int arow = lane & 15;          // point-within-16-tile (B' col)
  const int kq = (lane >> 4) * 8;

  f32x4 accA[4][2], accB[4][2];        // [point-tile][channel-tile]

  // weight A-frags (same bytes as R8's B-frags)
  auto loadW = [&](const _Float16* __restrict__ wl, int kt, f16x8 (&wfr)[2]) {
#pragma unroll
    for (int ntc = 0; ntc < 2; ++ntc)
      wfr[ntc] = *(const f16x8*)(wl + ((size_t)((kt * 16 + wc * 2 + ntc) * 64 + lane)) * 8);
  };
  // activation B'-frags: identical addresses to R8's A-frags
  auto loadA = [&](int T, int kt, f16x8 (&afr)[4]) {
    const int kof = kt * 32 + kq;
#pragma unroll
    for (int pt = 0; pt < 4; ++pt)
      afr[pt] = *(const f16x8*)(act + (T * 64 + pt * 16 + arow) * LDK + kof);
  };
  auto domfma = [&](f16x8 (&afr)[4], f16x8 (&wfr)[2], f32x4 (&acc)[4][2]) {
#pragma unroll
    for (int pt = 0; pt < 4; ++pt)
#pragma unroll
      for (int ntc = 0; ntc < 2; ++ntc)
        acc[pt][ntc] = __builtin_amdgcn_mfma_f32_16x16x32_f16(wfr[ntc], afr[pt], acc[pt][ntc], 0, 0, 0);
  };

  // epilogue group: s -> (pt = s>>1, ntc = s&1); lane holds 4 consecutive
  // channels of one point -> ONE contiguous b64 LDS write.
  auto epi_group = [&](int s, int T, f32x4 (&acc)[4][2], f32x4* cbq) {
    const int pt = s >> 1, ntc = s & 1;
    const int prow = T * 64 + pt * 16 + arow;
    const int chb = chq0 + ntc * 16;
    const float v0 = gelu_fast(fmaf(acc[pt][ntc][0], g1q[ntc][0], cbq[ntc][0]));
    const float v1 = gelu_fast(fmaf(acc[pt][ntc][1], g1q[ntc][1], cbq[ntc][1]));
    const float v2 = gelu_fast(fmaf(acc[pt][ntc][2], g1q[ntc][2], cbq[ntc][2]));
    const float v3 = gelu_fast(fmaf(acc[pt][ntc][3], g1q[ntc][3], cbq[ntc][3]));
    const h16x2 lo = __builtin_amdgcn_cvt_pkrtz(v0, v1);
    const h16x2 hi = __builtin_amdgcn_cvt_pkrtz(v2, v3);
    h16x4 pk;
    pk.x = lo.x; pk.y = lo.y; pk.z = hi.x; pk.w = hi.y;
    *(h16x4*)(act + prow * LDK + chb) = pk;
  };

  auto zero = [&](f32x4 (&acc)[4][2]) {
#pragma unroll
    for (int pt = 0; pt < 4; ++pt)
#pragma unroll
      for (int ntc = 0; ntc < 2; ++ntc)
        acc[pt][ntc] = (f32x4){0.f, 0.f, 0.f, 0.f};
  };

  f32x4 cbq[2];
  auto set_cb = [&](const float* __restrict__ bl) {
#pragma unroll
    for (int ntc = 0; ntc < 2; ++ntc) {
      const f32x4 bl4 = *(const f32x4*)&bl[chq0 + ntc * 16];
#pragma unroll
      for (int r = 0; r < 4; ++r)
        cbq[ntc][r] = fmaf(bl4[r], g1q[ntc][r], btq[ntc][r]);
    }
  };

  auto run_seg = [&](const _Float16* __restrict__ wl, int Kt, int Tk,
                     f32x4 (&accK)[4][2], bool do_epi, int Te,
                     f32x4 (&accE)[4][2]) {
    f16x8 bb[2][2];
    loadW(wl, 0, bb[0]);
    if (Kt > 1) loadW(wl, 1, bb[1]);
#pragma unroll
    for (int s = 0; s < 8; ++s) {
      if (s < Kt) {
        f16x8 afr[4];
        loadA(Tk, s, afr);
        domfma(afr, bb[s & 1], accK);
        if (s + 2 < Kt) loadW(wl, s + 2, bb[s & 1]);
      }
      if (do_epi) epi_group(s, Te, accE, cbq);
    }
  };

  const _Float16* wp0 = wpack + (size_t)KT0 * KTU;
  const _Float16* wp1 = wpack + (size_t)KT1 * KTU;
  const _Float16* wp2 = wpack + (size_t)KT2 * KTU;
  const _Float16* wp3 = wpack + (size_t)KT3 * KTU;

  // seg0: K(A,0)
  zero(accA);
  run_seg(wp0, 6, 0, accA, false, 0, accB);
  __syncthreads();

  // seg1: E(A,0) + K(B,0)
  zero(accB); set_cb(b0);
  run_seg(wp0, 6, 1, accB, true, 0, accA);
  __syncthreads();

  // seg2: E(B,0) + K(A,1)
  zero(accA); set_cb(b0);
  run_seg(wp1, 8, 0, accA, true, 1, accB);
  __syncthreads();

  // seg3: E(A,1) + K(B,1)
  zero(accB); set_cb(b1);
  run_seg(wp1, 8, 1, accB, true, 0, accA);
  __syncthreads();

  // seg4: E(B,1) + K(A,2)
  zero(accA); set_cb(b1);
  run_seg(wp2, 8, 0, accA, true, 1, accB);
  __syncthreads();

  // seg5: E(A,2) + K(B,2)
  zero(accB); set_cb(b2);
  run_seg(wp2, 8, 1, accB, true, 0, accA);
  __syncthreads();

  // seg6: E(B,2) + K(A,3)
  zero(accA); set_cb(b2);
  run_seg(wp3, 8, 0, accA, true, 1, accB);
  __syncthreads();

  // seg7: E(A,3) + K(B,3)
  zero(accB); set_cb(b3);
  run_seg(wp3, 8, 1, accB, true, 0, accA);
  __syncthreads();

  // seg8: E(B,3) [all waves] + Kout(tile A) [waves 0..3] + store A
  {
    set_cb(b3);
    const _Float16* wob = wpack + OUT_OFF;
    f32x4 oacc = (f32x4){0.f, 0.f, 0.f, 0.f};
    const int rb = (wc & 3) * 16 + ((wc < 4) ? 0 : 64);  // wave's 16-point slice
#pragma unroll
    for (int s = 0; s < 8; ++s) {
      if (wc < 4) {
        const f16x8 wfr = *(const f16x8*)(wob + (size_t)(s * 64 + lane) * 8);
        const f16x8 afr = *(const f16x8*)(act + (rb + arow) * LDK + s * 32 + kq);
        oacc = __builtin_amdgcn_mfma_f32_16x16x32_f16(wfr, afr, oacc, 0, 0, 0);
      }
      epi_group(s, 1, accB, cbq);
    }
    if (wc < 4 && (lane >> 4) == 0) {   // rows 0..3 hold out-channels; 0..2 valid
      const size_t o = ((size_t)b * NPTS + n0 + rb + arow) * 3;
      out[o + 0] = tanh_fast(oacc[0] + bo[0]);
      out[o + 1] = tanh_fast(oacc[1] + bo[1]);
      out[o + 2] = tanh_fast(oacc[2] + bo[2]);
    }
    __syncthreads();

    // seg9: Kout(tile B) [waves 4..7] + store B
    if (wc >= 4) {
      f32x4 oacc2 = (f32x4){0.f, 0.f, 0.f, 0.f};
#pragma unroll
      for (int kt = 0; kt < 8; ++kt) {
        const f16x8 wfr = *(const f16x8*)(wob + (size_t)(kt * 64 + lane) * 8);
        const f16x8 afr = *(const f16x8*)(act + (rb + arow) * LDK + kt * 32 + kq);
        oacc2 = __builtin_amdgcn_mfma_f32_16x16x32_f16(wfr, afr, oacc2, 0, 0, 0);
      }
      if ((lane >> 4) == 0) {
        const size_t o = ((size_t)b * NPTS + n0 + rb + arow) * 3;
        out[o + 0] = tanh_fast(oacc2[0] + bo[0]);
        out[o + 1] = tanh_fast(oacc2[1] + bo[1]);
        out[o + 2] = tanh_fast(oacc2[2] + bo[2]);
      }
    }
  }
}

extern "C" void kernel_launch(void* const* d_in, const int* in_sizes, int n_in,
                              void* d_out, int out_size, void* d_ws, size_t ws_size,
                              hipStream_t stream) {
  const float* grid   = (const float*)d_in[0];
  const float* ctx    = (const float*)d_in[1];
  const float* coords = (const float*)d_in[2];
  const float* w0 = (const float*)d_in[3];
  const float* b0 = (const float*)d_in[4];
  const float* w1 = (const float*)d_in[5];
  const float* b1 = (const float*)d_in[6];
  const float* w2 = (const float*)d_in[7];
  const float* b2 = (const float*)d_in[8];
  const float* w3 = (const float*)d_in[9];
  const float* b3 = (const float*)d_in[10];
  const float* wf = (const float*)d_in[11];
  const float* bf = (const float*)d_in[12];
  const float* wo = (const float*)d_in[13];
  const float* bo = (const float*)d_in[14];
  float* out = (float*)d_out;

  float* filmbuf = (float*)d_ws;
  _Float16* wpack = (_Float16*)((char*)d_ws + 8192);

  hipLaunchKernelGGL(prep_kernel, dim3(126), dim3(256), 0, stream,
                     w0, w1, w2, w3, wo, ctx, wf, bf, wpack, filmbuf);
  hipLaunchKernelGGL(decoder_kernel, dim3(NB * (NPTS / MT)), dim3(TPB), 0, stream,
                     grid, coords, b0, b1, b2, b3, bo, filmbuf, wpack, out);
}

// Round 14
// 264.260 us; speedup vs baseline: 1.1587x; 1.0577x over previous
//
#include <hip/hip_runtime.h>
#include <hip/hip_fp16.h>
#include <math.h>

#define NB 4
#define GH 64
#define GW 64
#define DM 128
#define MW 256
#define NF 10
#define NPTS 65536
#define ENCD 42
#define MT 128         // points per block: two 64-pt half-tiles A (rows 0-63) and B (64-127)
#define TPB 512
#define LDK 264        // act row stride in f16

typedef _Float16 f16x8 __attribute__((ext_vector_type(8)));
typedef __fp16 h16x2 __attribute__((ext_vector_type(2)));
typedef float f32x4 __attribute__((ext_vector_type(4)));

// d_ws: [0,8192) film fp32 (4x512); [8192,...) packed f16 weights.
// 16x16x32 B-frags: unit = (ktg*16 + nt)*64 + lane, 8 halves each.
#define KTU 8192
#define KT0 0
#define KT1 6
#define KT2 14
#define KT3 22
#define KT_TOTAL 30
#define NUNIT_MAIN (KT_TOTAL * 16 * 64)
#define NUNIT_OUT (8 * 64)
#define OUT_OFF ((size_t)NUNIT_MAIN * 8)

__device__ __forceinline__ float tanh_fast(float v) {
  const float e = __builtin_amdgcn_exp2f(2.8853900818f * v);
  return 1.0f - 2.0f * __builtin_amdgcn_rcpf(1.0f + e);
}

// Fused prep: blocks [0,122) pack weights; blocks [122,126) compute film.
__global__ void prep_kernel(const float* __restrict__ w0, const float* __restrict__ w1,
                            const float* __restrict__ w2, const float* __restrict__ w3,
                            const float* __restrict__ wo,
                            const float* __restrict__ ctx, const float* __restrict__ wf,
                            const float* __restrict__ bf,
                            _Float16* __restrict__ wp, float* __restrict__ filmout) {
  if (blockIdx.x >= 122) {
    const int b = blockIdx.x - 122;
#pragma unroll
    for (int h = 0; h < 2; ++h) {
      const int j = threadIdx.x + h * 256;
      float acc = bf[j];
      for (int k = 0; k < DM; ++k)
        acc = fmaf(ctx[b * DM + k], wf[k * 512 + j], acc);
      filmout[b * 512 + j] = acc;
    }
    return;
  }
  const int u = blockIdx.x * 256 + threadIdx.x;
  const int lane = u & 63;
  if (u < NUNIT_MAIN) {
    const int v = u >> 6;
    const int nt = v & 15;
    const int ktg = v >> 4;
    const float* w; int ktl, K;
    if (ktg < KT1)      { w = w0; ktl = ktg - KT0; K = 170; }
    else if (ktg < KT2) { w = w1; ktl = ktg - KT1; K = 256; }
    else if (ktg < KT3) { w = w2; ktl = ktg - KT2; K = 256; }
    else                { w = w3; ktl = ktg - KT3; K = 256; }
    const int n = nt * 16 + (lane & 15);
    const int kbase = ktl * 32 + (lane >> 4) * 8;
    _Float16* dst = wp + (size_t)u * 8;
#pragma unroll
    for (int j = 0; j < 8; ++j) {
      const int k = kbase + j;
      dst[j] = (_Float16)((k < K) ? w[k * MW + n] : 0.0f);
    }
  } else {
    const int kt = (u - NUNIT_MAIN) >> 6;
    const int col = lane & 15;
    const int kbase = kt * 32 + (lane >> 4) * 8;
    _Float16* dst = wp + (size_t)u * 8;
#pragma unroll
    for (int j = 0; j < 8; ++j)
      dst[j] = (_Float16)((col < 3) ? wo[(kbase + j) * 3 + col] : 0.0f);
  }
}

__global__ __launch_bounds__(TPB, 4) void decoder_kernel(
    const float* __restrict__ grid, const float* __restrict__ coords,
    const float* __restrict__ b0, const float* __restrict__ b1,
    const float* __restrict__ b2, const float* __restrict__ b3,
    const float* __restrict__ bo,
    const float* __restrict__ film, const _Float16* __restrict__ wpack,
    float* __restrict__ out) {
  __shared__ _Float16 act[MT * LDK];   // 67584 B; rows 0-63 = tile A, 64-127 = tile B
  __shared__ float4 cco4[MT];          // 2048 B

  const int tid = threadIdx.x;
  const int lane = tid & 63;
  const int wc = tid >> 6;             // wave 0..7: owns cols wc*32..wc*32+31 (disjoint)
  const int b = blockIdx.x >> 9;
  const int n0 = (blockIdx.x & 511) * MT;

  // packed-GELU constants (hoisted)
  const __half2 gk1 = __float2half2_rn(-2.3022082f);
  const __half2 gk2 = __float2half2_rn(-0.10294324f);
  const __half2 one2 = __float2half2_rn(1.0f);

  // ---- per-point bilinear setup ----
  if (tid < MT) {
    const float x = coords[(size_t)(n0 + tid) * 2 + 0];
    const float y = coords[(size_t)(n0 + tid) * 2 + 1];
    const float cr = (x + 1.0f) * 0.5f * 63.0f;
    const float cc = (y + 1.0f) * 0.5f * 63.0f;
    const float r0f = floorf(cr), q0f = floorf(cc);
    const int r0 = min(max((int)r0f, 0), GH - 1);
    const int q0 = min(max((int)q0f, 0), GW - 1);
    float4 v;
    v.x = __int_as_float(r0);
    v.y = __int_as_float(q0);
    v.z = cr - r0f;
    v.w = cc - q0f;
    cco4[tid] = v;
  }

  // ---- positional encoding (hw sin/cos, revolutions) + zero-pad 170..191 ----
  {
    const int p = tid & (MT - 1);
    const int j = tid >> 7;
    const float x = coords[(size_t)(n0 + p) * 2 + 0];
    const float y = coords[(size_t)(n0 + p) * 2 + 1];
    _Float16* row = act + p * LDK;
    if (j == 0) { row[0] = (_Float16)x; row[1] = (_Float16)y; }
    if (j == 1) {
      for (int c = ENCD + DM; c < ENCD + DM + 22; ++c) row[c] = (_Float16)0.0f;
    }
    for (int i = j; i < NF; i += 4) {
      const float sc = 0.5f * (float)(1 << i);
      const float rx = x * sc, ry = y * sc;
      const float fx = rx - floorf(rx);
      const float fy = ry - floorf(ry);
      row[2 + 4 * i + 0] = (_Float16)__builtin_amdgcn_sinf(fx);
      row[2 + 4 * i + 1] = (_Float16)__builtin_amdgcn_sinf(fy);
      row[2 + 4 * i + 2] = (_Float16)__builtin_amdgcn_cosf(fx);
      row[2 + 4 * i + 3] = (_Float16)__builtin_amdgcn_cosf(fy);
    }
  }
  __syncthreads();

  // ---- bilinear sampling, 4 channels/iter ----
  {
    const float* gb = grid + (size_t)b * (GH * GW * DM);
#pragma unroll
    for (int it = 0; it < (MT * DM / 4) / TPB; ++it) {
      const int idx = it * TPB + tid;
      const int p = idx >> 5;
      const int c = (idx & 31) * 4;
      const float4 cc4 = cco4[p];
      const int r0 = __float_as_int(cc4.x);
      const int q0 = __float_as_int(cc4.y);
      const float frr = cc4.z, frc = cc4.w;
      const int r1 = min(r0 + 1, GH - 1), q1 = min(q0 + 1, GW - 1);
      const float4 v00 = *(const float4*)(gb + (size_t)(r0 * GW + q0) * DM + c);
      const float4 v01 = *(const float4*)(gb + (size_t)(r0 * GW + q1) * DM + c);
      const float4 v10 = *(const float4*)(gb + (size_t)(r1 * GW + q0) * DM + c);
      const float4 v11 = *(const float4*)(gb + (size_t)(r1 * GW + q1) * DM + c);
      float4 vt, vb, vv;
      vt.x = fmaf(v01.x - v00.x, frc, v00.x);
      vt.y = fmaf(v01.y - v00.y, frc, v00.y);
      vt.z = fmaf(v01.z - v00.z, frc, v00.z);
      vt.w = fmaf(v01.w - v00.w, frc, v00.w);
      vb.x = fmaf(v11.x - v10.x, frc, v10.x);
      vb.y = fmaf(v11.y - v10.y, frc, v10.y);
      vb.z = fmaf(v11.z - v10.z, frc, v10.z);
      vb.w = fmaf(v11.w - v10.w, frc, v10.w);
      vv.x = fmaf(vb.x - vt.x, frr, vt.x);
      vv.y = fmaf(vb.y - vt.y, frr, vt.y);
      vv.z = fmaf(vb.z - vt.z, frr, vt.z);
      vv.w = fmaf(vb.w - vt.w, frr, vt.w);
      const h16x2 lo = __builtin_amdgcn_cvt_pkrtz(vv.x, vv.y);
      const h16x2 hi = __builtin_amdgcn_cvt_pkrtz(vv.z, vv.w);
      *(h16x2*)(act + p * LDK + ENCD + c) = lo;
      *(h16x2*)(act + p * LDK + ENCD + c + 2) = hi;
    }
  }

  // ---- FiLM params: this wave owns 2 n-tiles (cols wc*32 + nt*16 + 0..15) ----
  const int colbase = wc * 32 + (lane & 15);
  float g1[2], btv[2];
#pragma unroll
  for (int nt = 0; nt < 2; ++nt) {
    g1[nt] = film[b * 512 + colbase + nt * 16] + 1.0f;
    btv[nt] = film[b * 512 + MW + colbase + nt * 16];
  }
  __syncthreads();

  const int arow = lane & 15;
  const int kq = (lane >> 4) * 8;

  f32x4 accA[4][2], accB[4][2];

  // fragment loaders
  auto loadB = [&](const _Float16* __restrict__ wl, int kt, f16x8 (&bfr)[2]) {
#pragma unroll
    for (int nt = 0; nt < 2; ++nt)
      bfr[nt] = *(const f16x8*)(wl + ((size_t)((kt * 16 + wc * 2 + nt) * 64 + lane)) * 8);
  };
  auto loadA = [&](int T, int kt, f16x8 (&afr)[4]) {
    const int kof = kt * 32 + kq;
#pragma unroll
    for (int mt = 0; mt < 4; ++mt)
      afr[mt] = *(const f16x8*)(act + (T * 64 + mt * 16 + arow) * LDK + kof);
  };
  auto domfma = [&](f16x8 (&afr)[4], f16x8 (&bfr)[2], f32x4 (&acc)[4][2]) {
#pragma unroll
    for (int mt = 0; mt < 4; ++mt)
#pragma unroll
      for (int nt = 0; nt < 2; ++nt)
        acc[mt][nt] = __builtin_amdgcn_mfma_f32_16x16x32_f16(afr[mt], bfr[nt], acc[mt][nt], 0, 0, 0);
  };

  // packed-f16 GELU on a pair: g = h * rcp(1 + exp2(h * (gk1 + gk2*h^2)))
  auto gelu_pk = [&](h16x2 pk) -> h16x2 {
    __half2 hv = __builtin_bit_cast(__half2, pk);
    __half2 t = __hmul2(hv, hv);
    __half2 w = __hfma2(gk2, t, gk1);
    __half2 z = __hmul2(hv, w);
    __half2 e = h2exp2(z);
    __half2 s = __hadd2(e, one2);
    __half2 r = h2rcp(s);
    __half2 g = __hmul2(hv, r);
    return __builtin_bit_cast(h16x2, g);
  };

  // one epilogue group (of 8) for tile T: g -> (mt = g>>1, nt = g&1)
  auto epi_group = [&](int gI, int T, f32x4 (&acc)[4][2], const float* cbv) {
    const int mt = gI >> 1, nt = gI & 1;
    const int col = wc * 32 + nt * 16 + (lane & 15);
    const int rowb = T * 64 + mt * 16 + (lane >> 4) * 4;
    const float v0 = fmaf(acc[mt][nt][0], g1[nt], cbv[nt]);
    const float v1 = fmaf(acc[mt][nt][1], g1[nt], cbv[nt]);
    const float v2 = fmaf(acc[mt][nt][2], g1[nt], cbv[nt]);
    const float v3 = fmaf(acc[mt][nt][3], g1[nt], cbv[nt]);
    const h16x2 gA = gelu_pk(__builtin_amdgcn_cvt_pkrtz(v0, v1));
    const h16x2 gB = gelu_pk(__builtin_amdgcn_cvt_pkrtz(v2, v3));
    act[(rowb + 0) * LDK + col] = (_Float16)gA.x;
    act[(rowb + 1) * LDK + col] = (_Float16)gA.y;
    act[(rowb + 2) * LDK + col] = (_Float16)gB.x;
    act[(rowb + 3) * LDK + col] = (_Float16)gB.y;
  };

  auto zero = [&](f32x4 (&acc)[4][2]) {
#pragma unroll
    for (int mt = 0; mt < 4; ++mt)
#pragma unroll
      for (int nt = 0; nt < 2; ++nt)
        acc[mt][nt] = (f32x4){0.f, 0.f, 0.f, 0.f};
  };

  float cbv[2];
  auto set_cb = [&](const float* __restrict__ bl) {
#pragma unroll
    for (int nt = 0; nt < 2; ++nt)
      cbv[nt] = fmaf(bl[colbase + nt * 16], g1[nt], btv[nt]);
  };

  auto run_seg = [&](const _Float16* __restrict__ wl, int Kt, int Tk,
                     f32x4 (&accK)[4][2], bool do_epi, int Te,
                     f32x4 (&accE)[4][2]) {
    f16x8 bb[2][2];
    loadB(wl, 0, bb[0]);
    if (Kt > 1) loadB(wl, 1, bb[1]);
#pragma unroll
    for (int s = 0; s < 8; ++s) {
      if (s < Kt) {
        f16x8 afr[4];
        loadA(Tk, s, afr);
        domfma(afr, bb[s & 1], accK);
        if (s + 2 < Kt) loadB(wl, s + 2, bb[s & 1]);
      }
      if (do_epi) epi_group(s, Te, accE, cbv);
    }
  };

  const _Float16* wp0 = wpack + (size_t)KT0 * KTU;
  const _Float16* wp1 = wpack + (size_t)KT1 * KTU;
  const _Float16* wp2 = wpack + (size_t)KT2 * KTU;
  const _Float16* wp3 = wpack + (size_t)KT3 * KTU;

  // seg0: K(A,0)
  zero(accA);
  run_seg(wp0, 6, 0, accA, false, 0, accB);
  __syncthreads();

  // seg1: E(A,0) + K(B,0)
  zero(accB); set_cb(b0);
  run_seg(wp0, 6, 1, accB, true, 0, accA);
  __syncthreads();

  // seg2: E(B,0) + K(A,1)
  zero(accA); set_cb(b0);
  run_seg(wp1, 8, 0, accA, true, 1, accB);
  __syncthreads();

  // seg3: E(A,1) + K(B,1)
  zero(accB); set_cb(b1);
  run_seg(wp1, 8, 1, accB, true, 0, accA);
  __syncthreads();

  // seg4: E(B,1) + K(A,2)
  zero(accA); set_cb(b1);
  run_seg(wp2, 8, 0, accA, true, 1, accB);
  __syncthreads();

  // seg5: E(A,2) + K(B,2)
  zero(accB); set_cb(b2);
  run_seg(wp2, 8, 1, accB, true, 0, accA);
  __syncthreads();

  // seg6: E(B,2) + K(A,3)
  zero(accA); set_cb(b2);
  run_seg(wp3, 8, 0, accA, true, 1, accB);
  __syncthreads();

  // seg7: E(A,3) + K(B,3)
  zero(accB); set_cb(b3);
  run_seg(wp3, 8, 1, accB, true, 0, accA);
  __syncthreads();

  // seg8: E(B,3) [all waves] + Kout(tile A) [waves 0..3] + store A
  {
    set_cb(b3);
    const _Float16* wob = wpack + OUT_OFF;
    f32x4 oacc = (f32x4){0.f, 0.f, 0.f, 0.f};
    const int rb = (wc & 3) * 16 + ((wc < 4) ? 0 : 64);  // wave's 16-row slice
#pragma unroll
    for (int s = 0; s < 8; ++s) {
      if (wc < 4) {
        const f16x8 bfr = *(const f16x8*)(wob + (size_t)(s * 64 + lane) * 8);
        const f16x8 afr = *(const f16x8*)(act + (rb + arow) * LDK + s * 32 + kq);
        oacc = __builtin_amdgcn_mfma_f32_16x16x32_f16(afr, bfr, oacc, 0, 0, 0);
      }
      epi_group(s, 1, accB, cbv);
    }
    if (wc < 4) {
      const int col = lane & 15;
      if (col < 3) {
        const float bv = bo[col];
        const int rowb = rb + (lane >> 4) * 4;
#pragma unroll
        for (int r = 0; r < 4; ++r)
          out[((size_t)b * NPTS + n0 + rowb + r) * 3 + col] = tanh_fast(oacc[r] + bv);
      }
    }
    __syncthreads();

    // seg9: Kout(tile B) [waves 4..7] + store B
    if (wc >= 4) {
      f32x4 oacc2 = (f32x4){0.f, 0.f, 0.f, 0.f};
#pragma unroll
      for (int kt = 0; kt < 8; ++kt) {
        const f16x8 bfr = *(const f16x8*)(wob + (size_t)(kt * 64 + lane) * 8);
        const f16x8 afr = *(const f16x8*)(act + (rb + arow) * LDK + kt * 32 + kq);
        oacc2 = __builtin_amdgcn_mfma_f32_16x16x32_f16(afr, bfr, oacc2, 0, 0, 0);
      }
      const int col = lane & 15;
      if (col < 3) {
        const float bv = bo[col];
        const int rowb = rb + (lane >> 4) * 4;
#pragma unroll
        for (int r = 0; r < 4; ++r)
          out[((size_t)b * NPTS + n0 + rowb + r) * 3 + col] = tanh_fast(oacc2[r] + bv);
      }
    }
  }
}

extern "C" void kernel_launch(void* const* d_in, const int* in_sizes, int n_in,
                              void* d_out, int out_size, void* d_ws, size_t ws_size,
                              hipStream_t stream) {
  const float* grid   = (const float*)d_in[0];
  const float* ctx    = (const float*)d_in[1];
  const float* coords = (const float*)d_in[2];
  const float* w0 = (const float*)d_in[3];
  const float* b0 = (const float*)d_in[4];
  const float* w1 = (const float*)d_in[5];
  const float* b1 = (const float*)d_in[6];
  const float* w2 = (const float*)d_in[7];
  const float* b2 = (const float*)d_in[8];
  const float* w3 = (const float*)d_in[9];
  const float* b3 = (const float*)d_in[10];
  const float* wf = (const float*)d_in[11];
  const float* bf = (const float*)d_in[12];
  const float* wo = (const float*)d_in[13];
  const float* bo = (const float*)d_in[14];
  float* out = (float*)d_out;

  float* filmbuf = (float*)d_ws;
  _Float16* wpack = (_Float16*)((char*)d_ws + 8192);

  hipLaunchKernelGGL(prep_kernel, dim3(126), dim3(256), 0, stream,
                     w0, w1, w2, w3, wo, ctx, wf, bf, wpack, filmbuf);
  hipLaunchKernelGGL(decoder_kernel, dim3(NB * (NPTS / MT)), dim3(TPB), 0, stream,
                     grid, coords, b0, b1, b2, b3, bo, filmbuf, wpack, out);
}